// Round 1
// baseline (227.663 us; speedup 1.0000x reference)
//
#include <hip/hip_runtime.h>
#include <hip/hip_bf16.h>

#define C_ 8
#define B_ 32
#define G_ 2048
#define S_ 32
#define L_ 3
#define GAMMA_F 0.01f
#define INV_GAMMA_F 100.0f

// ws layout (floats):
//   [0,       524288)  buf0 : R_T (lse2, pre-global-normalize), layout [C][G][B]
//   [524288, 1048576)  buf1 : per-step clause result lse_r, layout [C][G][B]
//   [1048576,1048640)  max slots: clauseMax[4][8] then globalMax[4] (zeroed in init)

__device__ __forceinline__ void atomicMaxFloatPos(float* addr, float v) {
    // all values in this problem are >= 0, so uint compare == float compare
    atomicMax((unsigned int*)addr, __float_as_uint(v));
}

__global__ __launch_bounds__(256) void k_init(const float* __restrict__ x,
                                              float* __restrict__ buf0,
                                              float* __restrict__ maxslots) {
    int i = blockIdx.x * blockDim.x + threadIdx.x;   // over C*G*B = 524288
    int b = i & (B_ - 1);
    int g = (i >> 5) & (G_ - 1);
    buf0[i] = x[b * G_ + g];                         // R_T[c][g][b] = x[b][g]
    if (i < 64) maxslots[i] = 0.0f;
}

// One block = one clause c, 8 g's. Each wave: 2 g's x 32 b's (lane = b + 32*gpart).
__global__ __launch_bounds__(256) void k_clause(const float* __restrict__ R,   // buf0 [C][G][B]
                                                const int* __restrict__ I,     // [C][G][S][L]
                                                float* __restrict__ r_out,     // buf1 [C][G][B]
                                                const float* __restrict__ gmax_prev, // nullptr on step 0
                                                float* __restrict__ cmax_slot) // clauseMax + t*8
{
    __shared__ int sIdx[8 * S_ * L_];   // 768 ints
    __shared__ float sRed[4];

    const int GPB = 8;
    int bid = blockIdx.x;
    int c = bid / (G_ / GPB);
    int gbase = (bid % (G_ / GPB)) * GPB;
    int tid = threadIdx.x;

    // cooperative coalesced load of 768 indices
    const int* Ibase = I + (c * G_ + gbase) * (S_ * L_);
#pragma unroll
    for (int k = 0; k < 3; ++k) sIdx[tid + 256 * k] = Ibase[tid + 256 * k];
    __syncthreads();

    float gm = gmax_prev ? gmax_prev[0] : 0.0f;
    float sc = (gm > 1.0f) ? (1.0f / gm) : 1.0f;
    float sc3 = sc * sc * sc;

    int wave = tid >> 6;
    int lane = tid & 63;
    int b = lane & 31;
    int gloc = (wave << 1) | (lane >> 5);
    int g = gbase + gloc;

    const float* Rc = R + c * (G_ * B_);
    const int* myIdx = sIdx + gloc * (S_ * L_);

    float body[S_];
#pragma unroll
    for (int s = 0; s < S_; ++s) {
        int i0 = myIdx[s * 3 + 0];
        int i1 = myIdx[s * 3 + 1];
        int i2 = myIdx[s * 3 + 2];
        float v0 = Rc[(i0 << 5) | b];
        float v1 = Rc[(i1 << 5) | b];
        float v2 = Rc[(i2 << 5) | b];
        body[s] = v0 * v1 * v2 * sc3;
    }

    float mx = body[0];
#pragma unroll
    for (int s = 1; s < S_; ++s) mx = fmaxf(mx, body[s]);
    float sum = 0.0f;
#pragma unroll
    for (int s = 0; s < S_; ++s) sum += __expf((body[s] - mx) * INV_GAMMA_F);
    float lse = mx + GAMMA_F * __logf(sum);

    r_out[(c * G_ + g) * B_ + b] = lse;

    // block-level max -> per-clause atomic max
    float m = lse;
#pragma unroll
    for (int off = 32; off > 0; off >>= 1) m = fmaxf(m, __shfl_xor(m, off, 64));
    if (lane == 0) sRed[wave] = m;
    __syncthreads();
    if (tid == 0) {
        float mm = fmaxf(fmaxf(sRed[0], sRed[1]), fmaxf(sRed[2], sRed[3]));
        atomicMaxFloatPos(cmax_slot + c, mm);
    }
}

__global__ __launch_bounds__(256) void k_combine(float* __restrict__ R,          // buf0, in-place
                                                 const float* __restrict__ r_in, // buf1
                                                 const float* __restrict__ gmax_prev,
                                                 const float* __restrict__ cmax, // clauseMax + t*8
                                                 float* __restrict__ gmax_out)   // &globalMax[t]
{
    __shared__ float sRed[4];
    int i = blockIdx.x * blockDim.x + threadIdx.x;   // over 524288
    int c = i >> 16;                                  // G_*B_ = 65536 per clause

    float gm = gmax_prev ? gmax_prev[0] : 0.0f;
    float scR = (gm > 1.0f) ? (1.0f / gm) : 1.0f;
    float cm = cmax[c];
    float scr = (cm > 1.0f) ? (1.0f / cm) : 1.0f;

    float Rold = R[i] * scR;
    float rv = r_in[i] * scr;
    float M = fmaxf(Rold, rv);
    float mn = fminf(Rold, rv);
    float lse2 = M + GAMMA_F * log1pf(__expf((mn - M) * INV_GAMMA_F));
    R[i] = lse2;

    int lane = threadIdx.x & 63;
    int wave = threadIdx.x >> 6;
    float m = lse2;
#pragma unroll
    for (int off = 32; off > 0; off >>= 1) m = fmaxf(m, __shfl_xor(m, off, 64));
    if (lane == 0) sRed[wave] = m;
    __syncthreads();
    if (threadIdx.x == 0) {
        float mm = fmaxf(fmaxf(sRed[0], sRed[1]), fmaxf(sRed[2], sRed[3]));
        atomicMaxFloatPos(gmax_out, mm);
    }
}

// transpose [C][G][B] -> [C][B][G] with final global-max scale
__global__ __launch_bounds__(256) void k_out(const float* __restrict__ buf0,
                                             const float* __restrict__ gmax,
                                             float* __restrict__ out) {
    __shared__ float sT[64 * 33];   // 64 g x 32 b, padded stride 33
    int bid = blockIdx.x;           // C_ * (G_/64) = 256 blocks
    int c = bid >> 5;
    int g0 = (bid & 31) << 6;
    int tid = threadIdx.x;

    float gm = gmax[0];
    float sc = (gm > 1.0f) ? (1.0f / gm) : 1.0f;

    const float* src = buf0 + (c * G_ + g0) * B_;   // 64*32 contiguous floats
#pragma unroll
    for (int k = 0; k < 8; ++k) {
        int j = tid + 256 * k;                       // j = gg*32 + b
        sT[(j >> 5) * 33 + (j & 31)] = src[j] * sc;
    }
    __syncthreads();
#pragma unroll
    for (int k = 0; k < 8; ++k) {
        int j = tid + 256 * k;                       // j = b*64 + gg
        int b = j >> 6;
        int gg = j & 63;
        out[(c * B_ + b) * G_ + g0 + gg] = sT[gg * 33 + b];
    }
}

extern "C" void kernel_launch(void* const* d_in, const int* in_sizes, int n_in,
                              void* d_out, int out_size, void* d_ws, size_t ws_size,
                              hipStream_t stream) {
    const float* x = (const float*)d_in[0];
    const int* I = (const int*)d_in[1];
    float* out = (float*)d_out;
    float* ws = (float*)d_ws;

    float* buf0 = ws;
    float* buf1 = ws + 524288;
    float* maxs = ws + 1048576;
    float* clauseMax = maxs;        // [4][8]
    float* globalMax = maxs + 32;   // [4]

    k_init<<<2048, 256, 0, stream>>>(x, buf0, maxs);

    const float* gprev = nullptr;
    for (int t = 0; t < 4; ++t) {
        k_clause<<<2048, 256, 0, stream>>>(buf0, I, buf1, gprev, clauseMax + t * 8);
        k_combine<<<2048, 256, 0, stream>>>(buf0, buf1, gprev, clauseMax + t * 8,
                                            globalMax + t);
        gprev = globalMax + t;
    }

    k_out<<<256, 256, 0, stream>>>(buf0, globalMax + 3, out);
}